// Round 1
// baseline (222.017 us; speedup 1.0000x reference)
//
#include <hip/hip_runtime.h>
#include <math.h>

#define MU_PRIOR   0.6447f
#define LOGDET_SA  4.767705615349743f   /* 3*ln(4.9) */
#define INV_SA     (1.0f/4.9f)

__device__ __forceinline__ float warp_reduce_f(float v) {
#pragma unroll
    for (int off = 32; off > 0; off >>= 1) v += __shfl_down(v, off, 64);
    return v;
}

__device__ __forceinline__ double warp_reduce_d(double v) {
#pragma unroll
    for (int off = 32; off > 0; off >>= 1) v += __shfl_down(v, off, 64);
    return v;
}

// Each thread processes 4 consecutive rows -> all loads are aligned float4.
__global__ __launch_bounds__(256) void loss_main(
    const float* __restrict__ pred, const float* __restrict__ yobs,
    const float* __restrict__ rrs,  const float* __restrict__ rrsp,
    const float* __restrict__ nanarr, const float* __restrict__ cov,
    const float* __restrict__ mu, double* __restrict__ partial, int rows4)
{
    const int t = blockIdx.x * 256 + threadIdx.x;
    float acc = 0.0f;

    if (t < rows4) {
        const float4* P  = reinterpret_cast<const float4*>(pred)   + (size_t)9 * t;
        const float4* Y  = reinterpret_cast<const float4*>(yobs)   + (size_t)9 * t;
        const float4* NA = reinterpret_cast<const float4*>(nanarr) + (size_t)9 * t;
        const float4* R  = reinterpret_cast<const float4*>(rrs)    + (size_t)5 * t;
        const float4* RP = reinterpret_cast<const float4*>(rrsp)   + (size_t)5 * t;
        const float4* C  = reinterpret_cast<const float4*>(cov)    + (size_t)9 * t;
        const float4* M  = reinterpret_cast<const float4*>(mu)     + (size_t)3 * t;

        // ---- obs term: 10 * sum_r (sum_i dy^2) / lens_r ----
        float dy2[4]  = {0.f, 0.f, 0.f, 0.f};
        float lens[4] = {0.f, 0.f, 0.f, 0.f};
#pragma unroll
        for (int j = 0; j < 9; ++j) {
            float4 pv = P[j], yv = Y[j], nv = NA[j];
            const float pe[4] = {pv.x, pv.y, pv.z, pv.w};
            const float ye[4] = {yv.x, yv.y, yv.z, yv.w};
            const float ne[4] = {nv.x, nv.y, nv.z, nv.w};
#pragma unroll
            for (int k = 0; k < 4; ++k) {
                const int e = 4 * j + k;
                const int row = e / 9;              // compile-time after unroll
                const float d = pe[k] - ye[k];
                dy2[row]  += d * d;
                lens[row] += (ne[k] == ne[k]) ? 1.0f : 0.0f;  // !isnan
            }
        }
        acc += 10.0f * (dy2[0] / lens[0] + dy2[1] / lens[1] +
                        dy2[2] / lens[2] + dy2[3] / lens[3]);

        // ---- rrs term: sum dr^2 * w / 5 ----
        const float W[5] = {1.0f / (0.0015f * 0.0015f),
                            1.0f / (0.0012f * 0.0012f),
                            1.0f / (0.0010f * 0.0010f),
                            1.0f / (0.00086f * 0.00086f),
                            1.0f / (0.00057f * 0.00057f)};
        float racc = 0.f;
#pragma unroll
        for (int j = 0; j < 5; ++j) {
            float4 rv = R[j], qv = RP[j];
            const float re[4] = {rv.x, rv.y, rv.z, rv.w};
            const float qe[4] = {qv.x, qv.y, qv.z, qv.w};
#pragma unroll
            for (int k = 0; k < 4; ++k) {
                const int e = 4 * j + k;
                const int col = e % 5;              // compile-time after unroll
                const float d = re[k] - qe[k];
                racc += d * d * W[col];
            }
        }
        acc += racc * 0.2f;

        // ---- KL term: 0.5*(logdet_sa - log det(cov) + trace/4.9) per row ----
        float c[36];
#pragma unroll
        for (int j = 0; j < 9; ++j) {
            float4 v = C[j];
            c[4*j] = v.x; c[4*j+1] = v.y; c[4*j+2] = v.z; c[4*j+3] = v.w;
        }
#pragma unroll
        for (int r = 0; r < 4; ++r) {
            const float* m = c + 9 * r;
            const float tr  = m[0] + m[4] + m[8];
            const float det = m[0] * (m[4]*m[8] - m[5]*m[7])
                            - m[1] * (m[3]*m[8] - m[5]*m[6])
                            + m[2] * (m[3]*m[7] - m[4]*m[6]);
            acc += 0.5f * (LOGDET_SA - __logf(det) + tr * INV_SA);
        }

        // ---- mu term: sum dm^2 / (4.9 * 6) ----
        float dmacc = 0.f;
#pragma unroll
        for (int j = 0; j < 3; ++j) {
            float4 v = M[j];
            const float me[4] = {v.x, v.y, v.z, v.w};
#pragma unroll
            for (int k = 0; k < 4; ++k) {
                const float d = me[k] - MU_PRIOR;
                dmacc += d * d;
            }
        }
        acc += dmacc * (1.0f / 29.4f);
    }

    // block reduction -> double partial per block (deterministic, no atomics)
    acc = warp_reduce_f(acc);
    __shared__ float smem[4];
    const int lane = threadIdx.x & 63;
    const int wid  = threadIdx.x >> 6;
    if (lane == 0) smem[wid] = acc;
    __syncthreads();
    if (threadIdx.x == 0)
        partial[blockIdx.x] = (double)(smem[0] + smem[1] + smem[2] + smem[3]);
}

__global__ __launch_bounds__(256) void loss_final(
    const double* __restrict__ partial, int nblocks,
    const float* __restrict__ params, int nparams,
    const float* __restrict__ pred, const float* __restrict__ yobs,
    const float* __restrict__ rrs,  const float* __restrict__ rrsp,
    const float* __restrict__ nanarr, const float* __restrict__ cov,
    const float* __restrict__ mu, int rows, float* __restrict__ out)
{
    const int rows4 = rows >> 2;
    double accA = 0.0;   // per-row total (un-normalized)
    double accB = 0.0;   // l2 over parameters (un-normalized)

    for (int i = threadIdx.x; i < nblocks; i += 256) accA += partial[i];
    for (int i = threadIdx.x; i < nparams; i += 256) {
        const float d = params[i] - 1.0f;
        accB += (double)(d * d);
    }

    // tail rows (rows % 4) handled scalar here (dead for N=1e6)
    const int r = rows4 * 4 + (int)threadIdx.x;
    if (r < rows) {
        float dy2 = 0.f, len = 0.f;
        for (int i = 0; i < 9; ++i) {
            const float d = pred[9*r + i] - yobs[9*r + i];
            dy2 += d * d;
            const float v = nanarr[9*r + i];
            len += (v == v) ? 1.f : 0.f;
        }
        const float W[5] = {1.0f / (0.0015f * 0.0015f),
                            1.0f / (0.0012f * 0.0012f),
                            1.0f / (0.0010f * 0.0010f),
                            1.0f / (0.00086f * 0.00086f),
                            1.0f / (0.00057f * 0.00057f)};
        float racc = 0.f;
        for (int i = 0; i < 5; ++i) {
            const float d = rrs[5*r + i] - rrsp[5*r + i];
            racc += d * d * W[i];
        }
        const float* m = cov + 9 * (size_t)r;
        const float tr  = m[0] + m[4] + m[8];
        const float det = m[0] * (m[4]*m[8] - m[5]*m[7])
                        - m[1] * (m[3]*m[8] - m[5]*m[6])
                        + m[2] * (m[3]*m[7] - m[4]*m[6]);
        float dm = 0.f;
        for (int i = 0; i < 3; ++i) {
            const float d = mu[3*r + i] - MU_PRIOR;
            dm += d * d;
        }
        accA += (double)(racc * 0.2f + 10.f * dy2 / len
                         + 0.5f * (LOGDET_SA - __logf(det) + tr * INV_SA)
                         + dm * (1.f / 29.4f));
    }

    double val = accA * (1.0 / (double)rows) + accB * (1.0 / (double)nparams);
    val = warp_reduce_d(val);
    __shared__ double sm[4];
    const int lane = threadIdx.x & 63;
    const int wid  = threadIdx.x >> 6;
    if (lane == 0) sm[wid] = val;
    __syncthreads();
    if (threadIdx.x == 0)
        out[0] = (float)(sm[0] + sm[1] + sm[2] + sm[3]);
}

extern "C" void kernel_launch(void* const* d_in, const int* in_sizes, int n_in,
                              void* d_out, int out_size, void* d_ws, size_t ws_size,
                              hipStream_t stream) {
    const float* pred   = (const float*)d_in[0];
    const float* yobs   = (const float*)d_in[1];
    const float* rrs    = (const float*)d_in[2];
    const float* rrsp   = (const float*)d_in[3];
    const float* nanarr = (const float*)d_in[4];
    const float* cov    = (const float*)d_in[5];
    const float* mu     = (const float*)d_in[6];
    const float* params = (const float*)d_in[7];
    float* out = (float*)d_out;

    const int rows  = in_sizes[0] / 9;
    const int rows4 = rows / 4;
    int nblocks = (rows4 + 255) / 256;
    if (nblocks < 1) nblocks = 1;

    double* partial = (double*)d_ws;   // nblocks doubles; every entry written each call

    loss_main<<<nblocks, 256, 0, stream>>>(pred, yobs, rrs, rrsp, nanarr, cov, mu,
                                           partial, rows4);
    loss_final<<<1, 256, 0, stream>>>(partial, nblocks, params, in_sizes[7],
                                      pred, yobs, rrs, rrsp, nanarr, cov, mu,
                                      rows, out);
}